// Round 12
// baseline (616.054 us; speedup 1.0000x reference)
//
#include <hip/hip_runtime.h>

// ---------------------------------------------------------------------------
// GCN autoencoder, LDS-staged bf16-MFMA edition.
//   GEMMs: mfma_f32_16x16x32_bf16, 128xBN tile (BN=256), BK=32 DOUBLE-
//          BUFFERED (T3 minimum-2-phase: stage(kb+1) overlaps compute(kb),
//          one barrier per iter; LDS 48KB total -> 3 blocks/CU unchanged).
//          global_load_lds staging, source-side swizzle (rule #21);
//          GEMM1 reg-stages fp32 x directly.
//   1-D grid + bijective XCD chunk mapping (m204): col-blocks of one
//          row-block co-resident on one XCD -> A L2-shared (R11: -29 us).
//   Aggregation: CSR gather-sum over bf16 rows, UF=4 (512-dim) / UF=8 (128).
//   agg512 floor accepted: FETCH = 8 XCD x 51 MB table, structural.
// ---------------------------------------------------------------------------

typedef short bf16x8 __attribute__((ext_vector_type(8)));
typedef float f32x4 __attribute__((ext_vector_type(4)));
typedef float f32x2 __attribute__((ext_vector_type(2)));

__device__ __forceinline__ float bf2f(unsigned short u) {
  return __uint_as_float(((unsigned int)u) << 16);
}
__device__ __forceinline__ unsigned short f2bf(float f) {
  unsigned int u = __float_as_uint(f);
  return (unsigned short)((u + 0x7fffu + ((u >> 16) & 1u)) >> 16);  // RNE
}

__device__ __forceinline__ void gload_lds16(const void* g, void* l) {
  __builtin_amdgcn_global_load_lds(
      (const __attribute__((address_space(1))) unsigned int*)g,
      (__attribute__((address_space(3))) unsigned int*)l, 16, 0, 0);
}

// ---------------- graph preprocessing (CSR by dst) ----------------

__global__ void deg_hist_kernel(const int* __restrict__ dst, const float* __restrict__ ew,
                                float* __restrict__ deg, int* __restrict__ cnt, int E) {
  int e = blockIdx.x * blockDim.x + threadIdx.x;
  if (e >= E) return;
  int d = dst[e];
  atomicAdd(&deg[d], ew[e]);
  atomicAdd(&cnt[d], 1);
}

// per-block sum of cnt AND dinv computation (fused)
__global__ void block_sums_dinv_kernel(const int* __restrict__ cnt,
                                       const float* __restrict__ deg,
                                       int* __restrict__ sums,
                                       float* __restrict__ dinv, int n) {
  __shared__ int sh[512];
  int i = blockIdx.x * 512 + threadIdx.x;
  int v = 0;
  if (i < n) {
    v = cnt[i];
    dinv[i] = rsqrtf(deg[i] + 1.0f);
  }
  sh[threadIdx.x] = v;
  __syncthreads();
  for (int s = 256; s > 0; s >>= 1) {
    if (threadIdx.x < s) sh[threadIdx.x] += sh[threadIdx.x + s];
    __syncthreads();
  }
  if (threadIdx.x == 0) sums[blockIdx.x] = sh[0];
}

// single-block exclusive scan of block sums (nb <= 512)
__global__ void scan_sums_kernel(int* sums, int nb) {
  __shared__ int sh[512];
  int t = threadIdx.x;
  int v = (t < nb) ? sums[t] : 0;
  sh[t] = v;
  __syncthreads();
  for (int off = 1; off < 512; off <<= 1) {
    int y = (t >= off) ? sh[t - off] : 0;
    __syncthreads();
    sh[t] += y;
    __syncthreads();
  }
  if (t < nb) sums[t] = sh[t] - v;  // exclusive
}

__global__ void scan_final_kernel(const int* __restrict__ cnt, const int* __restrict__ sums,
                                  int* __restrict__ rowPtr, int* __restrict__ fill, int n) {
  __shared__ int sh[512];
  int i = blockIdx.x * 512 + threadIdx.x;
  int v = (i < n) ? cnt[i] : 0;
  sh[threadIdx.x] = v;
  __syncthreads();
  for (int off = 1; off < 512; off <<= 1) {
    int y = (threadIdx.x >= off) ? sh[threadIdx.x - off] : 0;
    __syncthreads();
    sh[threadIdx.x] += y;
    __syncthreads();
  }
  if (i < n) {
    int incl = sh[threadIdx.x];
    int base = sums[blockIdx.x];
    int excl = base + incl - v;
    rowPtr[i] = excl;
    fill[i] = excl;
    if (i == n - 1) rowPtr[n] = base + incl;
  }
}

__global__ void scatter_edges_kernel(const int* __restrict__ src, const int* __restrict__ dst,
                                     const float* __restrict__ ew, const float* __restrict__ dinv,
                                     int* __restrict__ fill, int2* __restrict__ pk, int E) {
  int e = blockIdx.x * blockDim.x + threadIdx.x;
  if (e >= E) return;
  int s = src[e], d = dst[e];
  int p = atomicAdd(&fill[d], 1);
  float v = dinv[s] * ew[e] * dinv[d];
  pk[p] = make_int2(s, __float_as_int(v));
}

// ---------------- weight bf16 convert, BK=32 swizzled tile layout ----------
// Per (nb, kb32): 512 chunks of 16B. Chunk c: col_in = c>>2, slot = c&3,
// slot holds global k-chunk (slot ^ (col_in&3)) — the LDS image directly.

__device__ __forceinline__ void tile_one(const float* __restrict__ W,
                                         short* __restrict__ hi,
                                         int K, int N, int g) {
  int kb_cnt = K >> 5;
  int c = g & 511;
  int t = g >> 9;
  int kb = t % kb_cnt;
  int nb = t / kb_cnt;
  int col_in = c >> 2;
  int slot = c & 3;
  int colg = (nb << 7) + col_in;
  int k0 = (kb << 5) + ((slot ^ (col_in & 3)) << 3);
  bf16x8 h8;
#pragma unroll
  for (int j = 0; j < 8; ++j) {
    float w = W[(size_t)(k0 + j) * N + colg];
    h8[j] = (short)f2bf(w);
  }
  *(bf16x8*)(hi + (size_t)g * 8) = h8;
}

// all four weights in one launch; chunk ranges are block-uniform
__global__ void tile_w4_kernel(const float* __restrict__ W1, short* __restrict__ h1,
                               const float* __restrict__ W2, short* __restrict__ h2,
                               const float* __restrict__ W3, short* __restrict__ h3,
                               const float* __restrict__ W4, short* __restrict__ h4) {
  int g = blockIdx.x * 256 + threadIdx.x;
  if (g < 32768) tile_one(W1, h1, 512, 512, g);                 // 4nb*16kb*512
  else if (g < 40960) tile_one(W2, h2, 512, 128, g - 32768);    // 1*16*512
  else if (g < 49152) tile_one(W3, h3, 128, 512, g - 40960);    // 4*4*512
  else tile_one(W4, h4, 512, 512, g - 49152);                   // 4*16*512
}

// ---------------- MFMA GEMM (dbuf LDS, BK=32): C[Mpad,N] bf16 = A * B ------
// BM=128, BN in {128,256}. Threads = 2*BN (4/8 waves), wave tile 64x64.
// 1-D grid nwg = NC * (Mpad/128); bijective XCD chunk mapping (m204).
// Per iter: stage(kb+1 into buf^1) issued BEFORE compute(kb, buf) — loads
// fly under ds_read+MFMA; single __syncthreads() per iter drains both.

template <int BN, int NC, bool AF32, bool BIAS, bool RELU>
__global__ __launch_bounds__(2 * BN) void mfma_gemm(
    const void* __restrict__ Aptr, const short* __restrict__ Bhi,
    const float* __restrict__ bias, unsigned short* __restrict__ C,
    int M, int N, int K) {
  constexpr int W = BN / 32;            // waves: 8 (BN256) / 4 (BN128)
  constexpr int IA = 512 / (64 * W);    // A stage issues: 1 / 2
  constexpr int NH = BN / 128;          // B 128-col panels: 2 / 1
  constexpr int IB = (512 * NH) / (64 * W);  // B stage issues: 2 / 2
  constexpr int CW = BN / 64;           // col-waves: 4 / 2

  __shared__ unsigned short As[2][4096];        // [buf][128 rows][4 slot][8]
  __shared__ unsigned short Bs[2][NH * 4096];   // [buf][panel][128 col][4 slot][8]

  // ---- bijective XCD chunk mapping (m204) ----
  const int nwg = gridDim.x;
  const int orig = blockIdx.x;
  const int xcd = orig & 7;
  const int idx = orig >> 3;
  const int q = nwg >> 3, r = nwg & 7;
  const int wgid = (xcd < r ? xcd * (q + 1) : r * (q + 1) + (xcd - r) * q) + idx;
  const int rowb = wgid / NC;
  const int colb = wgid - rowb * NC;

  const int tid = threadIdx.x;
  const int lane = tid & 63;
  const int wave = tid >> 6;
  const int rowblk = rowb << 7;
  const int colblk = colb * BN;
  const int wr = (wave / CW) << 6;
  const int wc = (wave % CW) << 6;
  const int lr = lane & 15;
  const int lk = lane >> 4;
  const int kbN = K >> 5;
  const int nb0 = colblk >> 7;

  f32x4 acc[4][4];
#pragma unroll
  for (int i = 0; i < 4; ++i)
#pragma unroll
    for (int j = 0; j < 4; ++j) {
      f32x4 z = {0.f, 0.f, 0.f, 0.f};
      acc[i][j] = z;
    }

  // per-thread A chunk ids and (row, swizzled k-offset) for staging
  int arow[IA], akoff[IA], admp[IA];
#pragma unroll
  for (int i = 0; i < IA; ++i) {
    int c = i * 64 * W + wave * 64 + lane;
    int row = c >> 2, slot = c & 3;
    int rg = rowblk + row;
    if (AF32) rg = (rg < M) ? rg : (M - 1);
    arow[i] = rg;
    akoff[i] = (slot ^ (row & 3)) << 3;
    admp[i] = c * 8;  // LDS elem offset for AF32 per-lane ds_write
  }

  auto stageA = [&](int buf, int kb) {
#pragma unroll
    for (int i = 0; i < IA; ++i) {
      if (AF32) {
        const float* ap = (const float*)Aptr + (size_t)arow[i] * K + (kb << 5) + akoff[i];
        float4 f0 = *(const float4*)ap;
        float4 f1 = *(const float4*)(ap + 4);
        bf16x8 t;
        t[0] = (short)f2bf(f0.x); t[1] = (short)f2bf(f0.y);
        t[2] = (short)f2bf(f0.z); t[3] = (short)f2bf(f0.w);
        t[4] = (short)f2bf(f1.x); t[5] = (short)f2bf(f1.y);
        t[6] = (short)f2bf(f1.z); t[7] = (short)f2bf(f1.w);
        *(bf16x8*)&As[buf][admp[i]] = t;
      } else {
        const unsigned short* src =
            (const unsigned short*)Aptr + (size_t)arow[i] * K + (kb << 5) + akoff[i];
        gload_lds16(src, &As[buf][(size_t)(i * 64 * W + wave * 64) * 8]);
      }
    }
  };

  auto stageB = [&](int buf, int kb) {
#pragma unroll
    for (int j = 0; j < IB; ++j) {
      int cB = j * 64 * W + wave * 64;       // wave-uniform chunk base
      int panel = cB >> 9;                    // uniform per issue
      int cin = (cB & 511) + lane;
      const short* src = Bhi + (((size_t)(nb0 + panel)) * kbN + kb) * 4096 + (size_t)cin * 8;
      gload_lds16(src, &Bs[buf][(size_t)cB * 8]);
    }
  };

  // prologue: stage kb=0 into buf 0
  stageA(0, 0);
  stageB(0, 0);
  __syncthreads();

  int buf = 0;
  for (int kb = 0; kb < kbN; ++kb) {
    if (kb + 1 < kbN) {                 // prefetch next tile under compute
      stageA(buf ^ 1, kb + 1);
      stageB(buf ^ 1, kb + 1);
    }
    bf16x8 af[4], bh[4];
#pragma unroll
    for (int rb = 0; rb < 4; ++rb) {
      int rowl = wr + rb * 16 + lr;
      af[rb] = *(const bf16x8*)&As[buf][rowl * 32 + ((lk ^ (rowl & 3)) << 3)];
    }
#pragma unroll
    for (int cb = 0; cb < 4; ++cb) {
      int coll = wc + cb * 16 + lr;
      bh[cb] = *(const bf16x8*)&Bs[buf][(coll >> 7) * 4096 + (coll & 127) * 32 +
                                        ((lk ^ (coll & 3)) << 3)];
    }
#pragma unroll
    for (int rb = 0; rb < 4; ++rb)
#pragma unroll
      for (int cb = 0; cb < 4; ++cb)
        acc[rb][cb] = __builtin_amdgcn_mfma_f32_16x16x32_bf16(af[rb], bh[cb], acc[rb][cb], 0, 0, 0);
    __syncthreads();                    // drains vmcnt (prefetch) + lds reads
    buf ^= 1;
  }

  // epilogue: C/D layout col=lane&15, row=(lane>>4)*4+i
#pragma unroll
  for (int cb = 0; cb < 4; ++cb) {
    int colg = colblk + wc + cb * 16 + lr;
    float badd = BIAS ? bias[colg] : 0.0f;
#pragma unroll
    for (int rb = 0; rb < 4; ++rb) {
#pragma unroll
      for (int i = 0; i < 4; ++i) {
        int row = rowblk + wr + rb * 16 + lk * 4 + i;
        float v = acc[rb][cb][i] + badd;
        if (RELU) v = fmaxf(v, 0.f);
        C[(size_t)row * N + colg] = f2bf(v);
      }
    }
  }
}

// ---------------- aggregation: out[i] = sum_e val[e]*xw[col[e]] + dinv^2*xw[i] ----

template <int PT, bool INF32>
__device__ __forceinline__ void load_row(const void* p, size_t off, float* xv) {
  if (INF32) {
    if (PT == 2) {
      f32x2 f = *(const f32x2*)((const float*)p + off);
      xv[0] = f[0]; xv[1] = f[1];
    } else {
      f32x4 f0 = *(const f32x4*)((const float*)p + off);
      f32x4 f1 = *(const f32x4*)((const float*)p + off + 4);
      xv[0] = f0[0]; xv[1] = f0[1]; xv[2] = f0[2]; xv[3] = f0[3];
      xv[4] = f1[0]; xv[5] = f1[1]; xv[6] = f1[2]; xv[7] = f1[3];
    }
  } else {
    if (PT == 2) {
      unsigned int u = *(const unsigned int*)((const unsigned short*)p + off);
      xv[0] = bf2f((unsigned short)(u & 0xffffu));
      xv[1] = bf2f((unsigned short)(u >> 16));
    } else {
      bf16x8 r = *(const bf16x8*)((const short*)p + off);
#pragma unroll
      for (int j = 0; j < 8; ++j) xv[j] = bf2f((unsigned short)r[j]);
    }
  }
}

template <int PT, int UF, bool INF32, bool BIAS, bool RELU, bool W32, bool W16>
__global__ __launch_bounds__(256) void agg_kernel(
    const void* __restrict__ xw, const int2* __restrict__ pk,
    const int* __restrict__ rowPtr, const float* __restrict__ dinv,
    const float* __restrict__ bias, float* __restrict__ out32,
    unsigned short* __restrict__ out16, int n) {
  const int DIM = PT * 64;
  int node = blockIdx.x * 4 + (threadIdx.x >> 6);
  if (node >= n) return;
  int t = threadIdx.x & 63;
  float acc[PT];
#pragma unroll
  for (int q = 0; q < PT; ++q) acc[q] = 0.f;

  int beg = rowPtr[node], end = rowPtr[node + 1];
  int e = beg;
  for (; e + UF <= end; e += UF) {
    int2 p[UF];
    float xv[UF][PT];
#pragma unroll
    for (int u = 0; u < UF; ++u) p[u] = pk[e + u];
#pragma unroll
    for (int u = 0; u < UF; ++u)
      load_row<PT, INF32>(xw, (size_t)p[u].x * DIM + t * PT, xv[u]);
#pragma unroll
    for (int u = 0; u < UF; ++u) {
      float v = __int_as_float(p[u].y);
#pragma unroll
      for (int q = 0; q < PT; ++q) acc[q] += v * xv[u][q];
    }
  }
  for (; e < end; ++e) {
    int2 pe = pk[e];
    float v = __int_as_float(pe.y);
    float xv[PT];
    load_row<PT, INF32>(xw, (size_t)pe.x * DIM + t * PT, xv);
#pragma unroll
    for (int q = 0; q < PT; ++q) acc[q] += v * xv[q];
  }
  float di = dinv[node];
  float sl = di * di;
  {
    float xv[PT];
    load_row<PT, INF32>(xw, (size_t)node * DIM + t * PT, xv);
#pragma unroll
    for (int q = 0; q < PT; ++q) acc[q] += sl * xv[q];
  }
  if (BIAS) {
#pragma unroll
    for (int q = 0; q < PT; ++q) acc[q] += bias[t * PT + q];
  }
  if (RELU) {
#pragma unroll
    for (int q = 0; q < PT; ++q) acc[q] = fmaxf(acc[q], 0.f);
  }
  if (W32) {
    if (PT == 2) {
      f32x2 o;
      o[0] = acc[0]; o[1] = acc[1];
      *(f32x2*)(out32 + (size_t)node * DIM + t * PT) = o;
    } else {
      f32x4 o0, o1;
      o0[0] = acc[0]; o0[1] = acc[1]; o0[2] = acc[2]; o0[3] = acc[3];
      o1[0] = acc[4 % PT]; o1[1] = acc[5 % PT]; o1[2] = acc[6 % PT]; o1[3] = acc[7 % PT];
      *(f32x4*)(out32 + (size_t)node * DIM + t * PT) = o0;
      *(f32x4*)(out32 + (size_t)node * DIM + t * PT + 4) = o1;
    }
  }
  if (W16) {
    if (PT == 2) {
      unsigned int u = (unsigned int)f2bf(acc[0]) | ((unsigned int)f2bf(acc[1]) << 16);
      *(unsigned int*)(out16 + (size_t)node * DIM + t * PT) = u;
    } else {
      bf16x8 o;
#pragma unroll
      for (int j = 0; j < PT; ++j) o[j % 8] = (short)f2bf(acc[j]);
      *(bf16x8*)(out16 + (size_t)node * DIM + t * PT) = o;
    }
  }
}

// ---------------------------------------------------------------------------

extern "C" void kernel_launch(void* const* d_in, const int* in_sizes, int n_in,
                              void* d_out, int out_size, void* d_ws, size_t ws_size,
                              hipStream_t stream) {
  const float* x  = (const float*)d_in[0];
  const int*   ei = (const int*)d_in[1];
  const float* ew = (const float*)d_in[2];
  const float* W1 = (const float*)d_in[3];
  const float* b1 = (const float*)d_in[4];
  const float* W2 = (const float*)d_in[5];
  const float* b2 = (const float*)d_in[6];
  const float* W3 = (const float*)d_in[7];
  const float* b3 = (const float*)d_in[8];
  const float* W4 = (const float*)d_in[9];
  const float* b4 = (const float*)d_in[10];

  const int n = in_sizes[0] / 512;         // 50000
  const int E = in_sizes[2];               // 800000
  const int MB128 = (n + 127) / 128;       // 391
  const int Mpad = MB128 * 128;            // 50048

  float* out   = (float*)d_out;
  float* z_out = out + (size_t)n * 512;

  // ---- workspace layout (~127 MB) ----
  char* w = (char*)d_ws;
  auto alloc = [&](size_t bytes) {
    char* p = w;
    w += (bytes + 255) & ~(size_t)255;
    return p;
  };
  float* deg    = (float*)alloc((size_t)n * 4);
  float* dinv   = (float*)alloc((size_t)n * 4);
  int*   cnt    = (int*)alloc((size_t)n * 4);
  int*   rowPtr = (int*)alloc((size_t)(n + 1) * 4);
  int*   fill   = (int*)alloc((size_t)n * 4);
  int*   sums   = (int*)alloc(4096);
  int2*  pk     = (int2*)alloc((size_t)E * 8);
  short* whi1 = (short*)alloc((size_t)512 * 512 * 2);
  short* whi2 = (short*)alloc((size_t)512 * 128 * 2);
  short* whi3 = (short*)alloc((size_t)128 * 512 * 2);
  short* whi4 = (short*)alloc((size_t)512 * 512 * 2);
  unsigned short* T  = (unsigned short*)alloc((size_t)Mpad * 128 * 2);  // xw2 / aggz
  unsigned short* B1 = (unsigned short*)alloc((size_t)Mpad * 512 * 2);  // h / xw4
  unsigned short* B2 = (unsigned short*)alloc((size_t)Mpad * 512 * 2);  // xw1 / zbf / h2

  unsigned short* zbf = B2;

  const int* srcp = ei;
  const int* dstp = ei + E;

  // ---- graph preprocessing ----
  hipMemsetAsync(deg, 0, (size_t)n * 4, stream);
  hipMemsetAsync(cnt, 0, (size_t)n * 4, stream);
  deg_hist_kernel<<<(E + 255) / 256, 256, 0, stream>>>(dstp, ew, deg, cnt, E);
  int NB = (n + 511) / 512;
  block_sums_dinv_kernel<<<NB, 512, 0, stream>>>(cnt, deg, sums, dinv, n);
  scan_sums_kernel<<<1, 512, 0, stream>>>(sums, NB);
  scan_final_kernel<<<NB, 512, 0, stream>>>(cnt, sums, rowPtr, fill, n);
  scatter_edges_kernel<<<(E + 255) / 256, 256, 0, stream>>>(srcp, dstp, ew, dinv, fill, pk, E);

  // ---- weight tiling (all four in one launch) ----
  tile_w4_kernel<<<320, 256, 0, stream>>>(W1, whi1, W2, whi2, W3, whi3, W4, whi4);

  const int AGB = (n + 3) / 4;  // 12500

  // ---- layer 1: xw1 = x@W1 (fp32 A, reg-staged) -> B2 ; h = relu(N.xw1+b1) -> B1 ----
  mfma_gemm<256, 2, true, false, false><<<2 * MB128, 512, 0, stream>>>(
      x, whi1, nullptr, B2, n, 512, 512);
  agg_kernel<8, 4, false, true, true, false, true><<<AGB, 256, 0, stream>>>(
      B2, pk, rowPtr, dinv, b1, nullptr, B1, n);

  // ---- layer 2: xw2 = h@W2 -> T ; z = N.xw2 + b2 -> z_out (fp32) + zbf ----
  mfma_gemm<128, 1, false, false, false><<<MB128, 256, 0, stream>>>(
      B1, whi2, nullptr, T, Mpad, 128, 512);
  agg_kernel<2, 8, false, true, false, true, true><<<AGB, 256, 0, stream>>>(
      T, pk, rowPtr, dinv, b2, z_out, zbf, n);

  // ---- layer 3: aggz = N.z (bf16 gather) -> T ; h2 = relu(aggz@W3+b3) -> B2 ----
  agg_kernel<2, 8, false, false, false, false, true><<<AGB, 256, 0, stream>>>(
      zbf, pk, rowPtr, dinv, nullptr, nullptr, T, n);
  mfma_gemm<256, 2, false, true, true><<<2 * MB128, 512, 0, stream>>>(
      T, whi3, b3, B2, Mpad, 512, 128);

  // ---- layer 4: xw4 = h2@W4 -> B1 ; x_recon = N.xw4 + b4 -> out (fp32) ----
  mfma_gemm<256, 2, false, false, false><<<2 * MB128, 512, 0, stream>>>(
      B2, whi4, nullptr, B1, Mpad, 512, 512);
  agg_kernel<8, 4, false, true, false, true, false><<<AGB, 256, 0, stream>>>(
      B1, pk, rowPtr, dinv, b4, out, nullptr, n);
}

// Round 13
// 598.895 us; speedup vs baseline: 1.0287x; 1.0287x over previous
//
#include <hip/hip_runtime.h>

// ---------------------------------------------------------------------------
// GCN autoencoder, LDS-staged bf16-MFMA edition.  (R11 structure restored —
// best measured 599.9 us; R12's BK=32 dbuf regressed: 2x barriers, half the
// MFMA per barrier, 4-way LDS conflicts at short K.)
//   GEMMs: mfma_f32_16x16x32_bf16, 128xBN tile (BN=256), BK=64,
//          single-buffered 2-barrier loop, global_load_lds staging with
//          source-side XOR swizzle (rule #21); GEMM1 reg-stages fp32 x.
//   1-D grid + bijective XCD chunk mapping (m204): both col-blocks of a
//          row-block co-resident on one XCD -> A fetched once (R11: -29 us).
//   Aggregation: CSR gather-sum over bf16 rows, UF=4 (512-dim) / UF=8 (128).
//   agg512 floor accepted: FETCH = 8 XCD x 51 MB table, structural.
//   deg/cnt adjacent -> single memset.
// ---------------------------------------------------------------------------

typedef short bf16x8 __attribute__((ext_vector_type(8)));
typedef float f32x4 __attribute__((ext_vector_type(4)));
typedef float f32x2 __attribute__((ext_vector_type(2)));

__device__ __forceinline__ float bf2f(unsigned short u) {
  return __uint_as_float(((unsigned int)u) << 16);
}
__device__ __forceinline__ unsigned short f2bf(float f) {
  unsigned int u = __float_as_uint(f);
  return (unsigned short)((u + 0x7fffu + ((u >> 16) & 1u)) >> 16);  // RNE
}

__device__ __forceinline__ void gload_lds16(const void* g, void* l) {
  __builtin_amdgcn_global_load_lds(
      (const __attribute__((address_space(1))) unsigned int*)g,
      (__attribute__((address_space(3))) unsigned int*)l, 16, 0, 0);
}

// ---------------- graph preprocessing (CSR by dst) ----------------

__global__ void deg_hist_kernel(const int* __restrict__ dst, const float* __restrict__ ew,
                                float* __restrict__ deg, int* __restrict__ cnt, int E) {
  int e = blockIdx.x * blockDim.x + threadIdx.x;
  if (e >= E) return;
  int d = dst[e];
  atomicAdd(&deg[d], ew[e]);
  atomicAdd(&cnt[d], 1);
}

// per-block sum of cnt AND dinv computation (fused)
__global__ void block_sums_dinv_kernel(const int* __restrict__ cnt,
                                       const float* __restrict__ deg,
                                       int* __restrict__ sums,
                                       float* __restrict__ dinv, int n) {
  __shared__ int sh[512];
  int i = blockIdx.x * 512 + threadIdx.x;
  int v = 0;
  if (i < n) {
    v = cnt[i];
    dinv[i] = rsqrtf(deg[i] + 1.0f);
  }
  sh[threadIdx.x] = v;
  __syncthreads();
  for (int s = 256; s > 0; s >>= 1) {
    if (threadIdx.x < s) sh[threadIdx.x] += sh[threadIdx.x + s];
    __syncthreads();
  }
  if (threadIdx.x == 0) sums[blockIdx.x] = sh[0];
}

// single-block exclusive scan of block sums (nb <= 512)
__global__ void scan_sums_kernel(int* sums, int nb) {
  __shared__ int sh[512];
  int t = threadIdx.x;
  int v = (t < nb) ? sums[t] : 0;
  sh[t] = v;
  __syncthreads();
  for (int off = 1; off < 512; off <<= 1) {
    int y = (t >= off) ? sh[t - off] : 0;
    __syncthreads();
    sh[t] += y;
    __syncthreads();
  }
  if (t < nb) sums[t] = sh[t] - v;  // exclusive
}

__global__ void scan_final_kernel(const int* __restrict__ cnt, const int* __restrict__ sums,
                                  int* __restrict__ rowPtr, int* __restrict__ fill, int n) {
  __shared__ int sh[512];
  int i = blockIdx.x * 512 + threadIdx.x;
  int v = (i < n) ? cnt[i] : 0;
  sh[threadIdx.x] = v;
  __syncthreads();
  for (int off = 1; off < 512; off <<= 1) {
    int y = (threadIdx.x >= off) ? sh[threadIdx.x - off] : 0;
    __syncthreads();
    sh[threadIdx.x] += y;
    __syncthreads();
  }
  if (i < n) {
    int incl = sh[threadIdx.x];
    int base = sums[blockIdx.x];
    int excl = base + incl - v;
    rowPtr[i] = excl;
    fill[i] = excl;
    if (i == n - 1) rowPtr[n] = base + incl;
  }
}

__global__ void scatter_edges_kernel(const int* __restrict__ src, const int* __restrict__ dst,
                                     const float* __restrict__ ew, const float* __restrict__ dinv,
                                     int* __restrict__ fill, int2* __restrict__ pk, int E) {
  int e = blockIdx.x * blockDim.x + threadIdx.x;
  if (e >= E) return;
  int s = src[e], d = dst[e];
  int p = atomicAdd(&fill[d], 1);
  float v = dinv[s] * ew[e] * dinv[d];
  pk[p] = make_int2(s, __float_as_int(v));
}

// ---------------- weight bf16 convert, swizzled 128-col tile layout --------
// Per (nb, kb): 1024 16B chunks. Chunk c: col = c>>3 (0..127), stored k-chunk
// kcs = c&7 holds global k-chunk (kcs ^ (col&7)) — the LDS image directly.

__device__ __forceinline__ void tile_one(const float* __restrict__ W,
                                         short* __restrict__ hi,
                                         int K, int N, int g) {
  int kb_cnt = K >> 6;
  int c = g & 1023;
  int t = g >> 10;
  int kb = t % kb_cnt;
  int nb = t / kb_cnt;
  int colg = (nb << 7) + (c >> 3);
  int k0 = (kb << 6) + (((c & 7) ^ ((c >> 3) & 7)) << 3);
  bf16x8 h8;
#pragma unroll
  for (int j = 0; j < 8; ++j) {
    float w = W[(size_t)(k0 + j) * N + colg];
    h8[j] = (short)f2bf(w);
  }
  *(bf16x8*)(hi + (size_t)g * 8) = h8;
}

// all four weights in one launch; chunk ranges are block-uniform (multiples of 256)
__global__ void tile_w4_kernel(const float* __restrict__ W1, short* __restrict__ h1,
                               const float* __restrict__ W2, short* __restrict__ h2,
                               const float* __restrict__ W3, short* __restrict__ h3,
                               const float* __restrict__ W4, short* __restrict__ h4) {
  int g = blockIdx.x * 256 + threadIdx.x;
  if (g < 32768) tile_one(W1, h1, 512, 512, g);                 // 4nb*8kb*1024
  else if (g < 40960) tile_one(W2, h2, 512, 128, g - 32768);    // 1*8*1024
  else if (g < 49152) tile_one(W3, h3, 128, 512, g - 40960);    // 4*2*1024
  else tile_one(W4, h4, 512, 512, g - 49152);                   // 4*8*1024
}

// ---------------- MFMA GEMM (LDS-staged): C[Mpad,N] bf16 = A * B ----------
// BM=128, BN in {128,256}, BK=64. Threads = 2*BN (4/8 waves), wave tile
// 64x64. 1-D grid nwg = NC * (Mpad/128); bijective XCD chunk mapping (m204)
// puts consecutive wgids (= both col-blocks of one row-block) on one XCD.
// AF32: A is fp32, reg-staged with convert.

template <int BN, int NC, bool AF32, bool BIAS, bool RELU>
__global__ __launch_bounds__(2 * BN) void mfma_gemm(
    const void* __restrict__ Aptr, const short* __restrict__ Bhi,
    const float* __restrict__ bias, unsigned short* __restrict__ C,
    int M, int N, int K) {
  constexpr int W = BN / 32;       // waves
  constexpr int RW = 128 / W;      // A rows per wave
  constexpr int IA = RW / 8;       // A stage issues per thread
  constexpr int NH = BN / 128;     // 128-col halves
  constexpr int WH = W / NH;       // waves per half: 4
  constexpr int CW = BN / 64;      // wave cols

  __shared__ short As[8192];       // [128 rows][8 kc][8] swizzled image
  __shared__ short Bs[BN * 64];    // [BN cols][8 kc][8]

  // ---- bijective XCD chunk mapping (m204) ----
  const int nwg = gridDim.x;
  const int orig = blockIdx.x;
  const int xcd = orig & 7;
  const int idx = orig >> 3;
  const int q = nwg >> 3, r = nwg & 7;
  const int wgid = (xcd < r ? xcd * (q + 1) : r * (q + 1) + (xcd - r) * q) + idx;
  const int rowb = wgid / NC;
  const int colb = wgid - rowb * NC;

  const int tid = threadIdx.x;
  const int lane = tid & 63;
  const int wave = tid >> 6;
  const int rowblk = rowb << 7;
  const int colblk = colb * BN;
  const int wr = (wave / CW) << 6;
  const int wc = (wave % CW) << 6;
  const int lr = lane & 15;
  const int lk = lane >> 4;
  const int kbN = K >> 6;
  const int half = wave / WH;
  const int wh = wave % WH;
  const int nb0 = colblk >> 7;

  f32x4 acc[4][4];
#pragma unroll
  for (int i = 0; i < 4; ++i)
#pragma unroll
    for (int j = 0; j < 4; ++j) {
      f32x4 z = {0.f, 0.f, 0.f, 0.f};
      acc[i][j] = z;
    }

  size_t aoff[IA];
#pragma unroll
  for (int i = 0; i < IA; ++i) {
    int rg = rowblk + wave * RW + i * 8 + (lane >> 3);
    if (AF32) rg = (rg < M) ? rg : (M - 1);
    aoff[i] = (size_t)rg * K + (size_t)(((lane & 7) ^ ((lane >> 3) & 7)) << 3);
  }
  short* AsW = As + wave * (RW * 64);
  short* BsW = Bs + half * 8192 + wh * 2048;

  for (int kb = 0; kb < kbN; ++kb) {
    const short* bsrc = Bhi + ((size_t)(nb0 + half) * kbN + kb) * 8192 + (size_t)(wh * 256 + lane) * 8;
#pragma unroll
    for (int i = 0; i < 4; ++i)
      gload_lds16(bsrc + i * 512, BsW + i * 512);
#pragma unroll
    for (int i = 0; i < IA; ++i) {
      if (AF32) {
        const float* ap = (const float*)Aptr + aoff[i] + (kb << 6);
        float4 f0 = *(const float4*)ap;
        float4 f1 = *(const float4*)(ap + 4);
        bf16x8 t;
        t[0] = (short)f2bf(f0.x); t[1] = (short)f2bf(f0.y);
        t[2] = (short)f2bf(f0.z); t[3] = (short)f2bf(f0.w);
        t[4] = (short)f2bf(f1.x); t[5] = (short)f2bf(f1.y);
        t[6] = (short)f2bf(f1.z); t[7] = (short)f2bf(f1.w);
        *(bf16x8*)(AsW + i * 512 + lane * 8) = t;
      } else {
        gload_lds16((const unsigned short*)Aptr + aoff[i] + (kb << 6), AsW + i * 512);
      }
    }
    __syncthreads();
#pragma unroll
    for (int kk = 0; kk < 2; ++kk) {
      bf16x8 af[4], bhf[4];
      const int kc = kk * 4 + lk;
#pragma unroll
      for (int rb = 0; rb < 4; ++rb) {
        int rowl = wr + rb * 16 + lr;
        af[rb] = *(const bf16x8*)(As + rowl * 64 + ((kc ^ (rowl & 7)) << 3));
      }
#pragma unroll
      for (int cb = 0; cb < 4; ++cb) {
        int coll = wc + cb * 16 + lr;
        bhf[cb] = *(const bf16x8*)(Bs + coll * 64 + ((kc ^ (coll & 7)) << 3));
      }
#pragma unroll
      for (int rb = 0; rb < 4; ++rb)
#pragma unroll
        for (int cb = 0; cb < 4; ++cb)
          acc[rb][cb] = __builtin_amdgcn_mfma_f32_16x16x32_bf16(af[rb], bhf[cb], acc[rb][cb], 0, 0, 0);
    }
    __syncthreads();
  }

  // epilogue: C/D layout col=lane&15, row=(lane>>4)*4+i
#pragma unroll
  for (int cb = 0; cb < 4; ++cb) {
    int colg = colblk + wc + cb * 16 + lr;
    float badd = BIAS ? bias[colg] : 0.0f;
#pragma unroll
    for (int rb = 0; rb < 4; ++rb) {
#pragma unroll
      for (int i = 0; i < 4; ++i) {
        int row = rowblk + wr + rb * 16 + lk * 4 + i;
        float v = acc[rb][cb][i] + badd;
        if (RELU) v = fmaxf(v, 0.f);
        C[(size_t)row * N + colg] = f2bf(v);
      }
    }
  }
}

// ---------------- aggregation: out[i] = sum_e val[e]*xw[col[e]] + dinv^2*xw[i] ----

template <int PT, bool INF32>
__device__ __forceinline__ void load_row(const void* p, size_t off, float* xv) {
  if (INF32) {
    if (PT == 2) {
      f32x2 f = *(const f32x2*)((const float*)p + off);
      xv[0] = f[0]; xv[1] = f[1];
    } else {
      f32x4 f0 = *(const f32x4*)((const float*)p + off);
      f32x4 f1 = *(const f32x4*)((const float*)p + off + 4);
      xv[0] = f0[0]; xv[1] = f0[1]; xv[2] = f0[2]; xv[3] = f0[3];
      xv[4] = f1[0]; xv[5] = f1[1]; xv[6] = f1[2]; xv[7] = f1[3];
    }
  } else {
    if (PT == 2) {
      unsigned int u = *(const unsigned int*)((const unsigned short*)p + off);
      xv[0] = bf2f((unsigned short)(u & 0xffffu));
      xv[1] = bf2f((unsigned short)(u >> 16));
    } else {
      bf16x8 r = *(const bf16x8*)((const short*)p + off);
#pragma unroll
      for (int j = 0; j < 8; ++j) xv[j] = bf2f((unsigned short)r[j]);
    }
  }
}

template <int PT, int UF, bool INF32, bool BIAS, bool RELU, bool W32, bool W16>
__global__ __launch_bounds__(256) void agg_kernel(
    const void* __restrict__ xw, const int2* __restrict__ pk,
    const int* __restrict__ rowPtr, const float* __restrict__ dinv,
    const float* __restrict__ bias, float* __restrict__ out32,
    unsigned short* __restrict__ out16, int n) {
  const int DIM = PT * 64;
  int node = blockIdx.x * 4 + (threadIdx.x >> 6);
  if (node >= n) return;
  int t = threadIdx.x & 63;
  float acc[PT];
#pragma unroll
  for (int q = 0; q < PT; ++q) acc[q] = 0.f;

  int beg = rowPtr[node], end = rowPtr[node + 1];
  int e = beg;
  for (; e + UF <= end; e += UF) {
    int2 p[UF];
    float xv[UF][PT];
#pragma unroll
    for (int u = 0; u < UF; ++u) p[u] = pk[e + u];
#pragma unroll
    for (int u = 0; u < UF; ++u)
      load_row<PT, INF32>(xw, (size_t)p[u].x * DIM + t * PT, xv[u]);
#pragma unroll
    for (int u = 0; u < UF; ++u) {
      float v = __int_as_float(p[u].y);
#pragma unroll
      for (int q = 0; q < PT; ++q) acc[q] += v * xv[u][q];
    }
  }
  for (; e < end; ++e) {
    int2 pe = pk[e];
    float v = __int_as_float(pe.y);
    float xv[PT];
    load_row<PT, INF32>(xw, (size_t)pe.x * DIM + t * PT, xv);
#pragma unroll
    for (int q = 0; q < PT; ++q) acc[q] += v * xv[q];
  }
  float di = dinv[node];
  float sl = di * di;
  {
    float xv[PT];
    load_row<PT, INF32>(xw, (size_t)node * DIM + t * PT, xv);
#pragma unroll
    for (int q = 0; q < PT; ++q) acc[q] += sl * xv[q];
  }
  if (BIAS) {
#pragma unroll
    for (int q = 0; q < PT; ++q) acc[q] += bias[t * PT + q];
  }
  if (RELU) {
#pragma unroll
    for (int q = 0; q < PT; ++q) acc[q] = fmaxf(acc[q], 0.f);
  }
  if (W32) {
    if (PT == 2) {
      f32x2 o;
      o[0] = acc[0]; o[1] = acc[1];
      *(f32x2*)(out32 + (size_t)node * DIM + t * PT) = o;
    } else {
      f32x4 o0, o1;
      o0[0] = acc[0]; o0[1] = acc[1]; o0[2] = acc[2]; o0[3] = acc[3];
      o1[0] = acc[4 % PT]; o1[1] = acc[5 % PT]; o1[2] = acc[6 % PT]; o1[3] = acc[7 % PT];
      *(f32x4*)(out32 + (size_t)node * DIM + t * PT) = o0;
      *(f32x4*)(out32 + (size_t)node * DIM + t * PT + 4) = o1;
    }
  }
  if (W16) {
    if (PT == 2) {
      unsigned int u = (unsigned int)f2bf(acc[0]) | ((unsigned int)f2bf(acc[1]) << 16);
      *(unsigned int*)(out16 + (size_t)node * DIM + t * PT) = u;
    } else {
      bf16x8 o;
#pragma unroll
      for (int j = 0; j < PT; ++j) o[j % 8] = (short)f2bf(acc[j]);
      *(bf16x8*)(out16 + (size_t)node * DIM + t * PT) = o;
    }
  }
}

// ---------------------------------------------------------------------------

extern "C" void kernel_launch(void* const* d_in, const int* in_sizes, int n_in,
                              void* d_out, int out_size, void* d_ws, size_t ws_size,
                              hipStream_t stream) {
  const float* x  = (const float*)d_in[0];
  const int*   ei = (const int*)d_in[1];
  const float* ew = (const float*)d_in[2];
  const float* W1 = (const float*)d_in[3];
  const float* b1 = (const float*)d_in[4];
  const float* W2 = (const float*)d_in[5];
  const float* b2 = (const float*)d_in[6];
  const float* W3 = (const float*)d_in[7];
  const float* b3 = (const float*)d_in[8];
  const float* W4 = (const float*)d_in[9];
  const float* b4 = (const float*)d_in[10];

  const int n = in_sizes[0] / 512;         // 50000
  const int E = in_sizes[2];               // 800000
  const int MB128 = (n + 127) / 128;       // 391
  const int Mpad = MB128 * 128;            // 50048

  float* out   = (float*)d_out;
  float* z_out = out + (size_t)n * 512;

  // ---- workspace layout (~127 MB) ----
  char* w = (char*)d_ws;
  auto alloc = [&](size_t bytes) {
    char* p = w;
    w += (bytes + 255) & ~(size_t)255;
    return p;
  };
  const size_t nbr = ((size_t)n * 4 + 255) & ~(size_t)255;
  float* deg    = (float*)alloc((size_t)n * 4);  // deg & cnt adjacent: 1 memset
  int*   cnt    = (int*)alloc((size_t)n * 4);
  float* dinv   = (float*)alloc((size_t)n * 4);
  int*   rowPtr = (int*)alloc((size_t)(n + 1) * 4);
  int*   fill   = (int*)alloc((size_t)n * 4);
  int*   sums   = (int*)alloc(4096);
  int2*  pk     = (int2*)alloc((size_t)E * 8);
  short* whi1 = (short*)alloc((size_t)512 * 512 * 2);
  short* whi2 = (short*)alloc((size_t)512 * 128 * 2);
  short* whi3 = (short*)alloc((size_t)128 * 512 * 2);
  short* whi4 = (short*)alloc((size_t)512 * 512 * 2);
  unsigned short* T  = (unsigned short*)alloc((size_t)Mpad * 128 * 2);  // xw2 / aggz
  unsigned short* B1 = (unsigned short*)alloc((size_t)Mpad * 512 * 2);  // h / xw4
  unsigned short* B2 = (unsigned short*)alloc((size_t)Mpad * 512 * 2);  // xw1 / zbf / h2

  unsigned short* zbf = B2;

  const int* srcp = ei;
  const int* dstp = ei + E;

  // ---- graph preprocessing ----
  hipMemsetAsync(deg, 0, 2 * nbr, stream);  // zeroes deg AND cnt (adjacent)
  deg_hist_kernel<<<(E + 255) / 256, 256, 0, stream>>>(dstp, ew, deg, cnt, E);
  int NB = (n + 511) / 512;
  block_sums_dinv_kernel<<<NB, 512, 0, stream>>>(cnt, deg, sums, dinv, n);
  scan_sums_kernel<<<1, 512, 0, stream>>>(sums, NB);
  scan_final_kernel<<<NB, 512, 0, stream>>>(cnt, sums, rowPtr, fill, n);
  scatter_edges_kernel<<<(E + 255) / 256, 256, 0, stream>>>(srcp, dstp, ew, dinv, fill, pk, E);

  // ---- weight tiling (all four in one launch) ----
  tile_w4_kernel<<<320, 256, 0, stream>>>(W1, whi1, W2, whi2, W3, whi3, W4, whi4);

  const int AGB = (n + 3) / 4;  // 12500

  // ---- layer 1: xw1 = x@W1 (fp32 A, reg-staged) -> B2 ; h = relu(N.xw1+b1) -> B1 ----
  mfma_gemm<256, 2, true, false, false><<<2 * MB128, 512, 0, stream>>>(
      x, whi1, nullptr, B2, n, 512, 512);
  agg_kernel<8, 4, false, true, true, false, true><<<AGB, 256, 0, stream>>>(
      B2, pk, rowPtr, dinv, b1, nullptr, B1, n);

  // ---- layer 2: xw2 = h@W2 -> T ; z = N.xw2 + b2 -> z_out (fp32) + zbf ----
  mfma_gemm<128, 1, false, false, false><<<MB128, 256, 0, stream>>>(
      B1, whi2, nullptr, T, Mpad, 128, 512);
  agg_kernel<2, 8, false, true, false, true, true><<<AGB, 256, 0, stream>>>(
      T, pk, rowPtr, dinv, b2, z_out, zbf, n);

  // ---- layer 3: aggz = N.z (bf16 gather) -> T ; h2 = relu(aggz@W3+b3) -> B2 ----
  agg_kernel<2, 8, false, false, false, false, true><<<AGB, 256, 0, stream>>>(
      zbf, pk, rowPtr, dinv, nullptr, nullptr, T, n);
  mfma_gemm<256, 2, false, true, true><<<2 * MB128, 512, 0, stream>>>(
      T, whi3, b3, B2, Mpad, 512, 128);

  // ---- layer 4: xw4 = h2@W4 -> B1 ; x_recon = N.xw4 + b4 -> out (fp32) ----
  mfma_gemm<256, 2, false, false, false><<<2 * MB128, 512, 0, stream>>>(
      B2, whi4, nullptr, B1, Mpad, 512, 512);
  agg_kernel<8, 4, false, true, false, true, false><<<AGB, 256, 0, stream>>>(
      B1, pk, rowPtr, dinv, b4, out, nullptr, n);
}